// Round 1
// baseline (9510.463 us; speedup 1.0000x reference)
//
#include <hip/hip_runtime.h>

// RNN scan on MI355X.
// Phase 1 (k1): xw[t][b][:] = bf16(x[b,t,:] @ W_x) + b_x + b_h, stored bf16 t-major.
// Phase 2 (k2): persistent scan, 8 clusters (8 batch rows) x 8 WGs (64 cols).
//   W_h column-slice lives in VGPRs as pre-swizzled MFMA B-fragments (survives
//   the per-step acquire-fence cache invalidation). h double-buffered in global,
//   monotonic arrival counter per cluster for the per-step barrier.
// Phase 3 (k3): out[b] = h_T[b,:] @ W_fc + b_fc.

#define T_STEPS 1024
#define BATCH   64
#define HID     512

typedef __attribute__((ext_vector_type(8))) short  short8;   // 8 bf16 = 4 VGPRs (MFMA A/B frag)
typedef __attribute__((ext_vector_type(4))) float  f32x4;    // MFMA C/D frag

typedef unsigned short ushort_t;
typedef unsigned int   uint_t;

__device__ __forceinline__ ushort_t f2bf(float f) {
    union { float f; uint_t u; } c; c.f = f;
    uint_t u = c.u;
    uint_t r = (u + 0x7fffu + ((u >> 16) & 1u)) >> 16;   // RNE
    return (ushort_t)r;
}
__device__ __forceinline__ float bf2f(ushort_t h) {
    union { uint_t u; float f; } c; c.u = ((uint_t)h) << 16;
    return c.f;
}

// ---------------------------------------------------------------------------
// k1: xw = x @ W_x + (b_x + b_h).  M=65536 (t-major: m = t*64 + b), N=K=512.
// 64x64 tile per WG (one t, all 64 b), BK=32, 4 waves each own 16 N-cols.
// ---------------------------------------------------------------------------
__global__ __launch_bounds__(256) void k1_xproj(
    const float* __restrict__ x, const float* __restrict__ Wx,
    const float* __restrict__ bx, const float* __restrict__ bh,
    ushort_t* __restrict__ xw)
{
    __shared__ __align__(16) ushort_t Al[64 * 32];   // [row b][k] bf16
    __shared__ __align__(16) ushort_t Bl[64 * 32];   // [n][k] bf16 (swizzled for B-frag reads)

    const int t0   = blockIdx.y;
    const int n0   = blockIdx.x * 64;
    const int tid  = threadIdx.x;
    const int wave = tid >> 6;
    const int lane = tid & 63;
    const int lm   = lane & 15;
    const int quad = lane >> 4;

    f32x4 acc[4];
    #pragma unroll
    for (int i = 0; i < 4; ++i) acc[i] = (f32x4){0.f, 0.f, 0.f, 0.f};

    const int ar = tid >> 2, ac = (tid & 3) * 8;   // A staging: row 0..63, 8 k's
    const int bk = tid >> 3, bc = (tid & 7) * 8;   // B staging: k 0..31, 8 n's

    for (int kb = 0; kb < 16; ++kb) {
        { // stage A: x[b=ar][t0][kb*32+ac .. +8]  fp32 -> bf16
            const float* ap = x + ((size_t)ar * T_STEPS + t0) * HID + kb * 32 + ac;
            short8 pack;
            #pragma unroll
            for (int i = 0; i < 8; ++i) pack[i] = (short)f2bf(ap[i]);
            *(short8*)&Al[ar * 32 + ac] = pack;
        }
        { // stage B swizzled: Bl[n][k] = Wx[kb*32+bk][n0+bc+i]
            const float* bp = Wx + (size_t)(kb * 32 + bk) * HID + n0 + bc;
            #pragma unroll
            for (int i = 0; i < 8; ++i) Bl[(bc + i) * 32 + bk] = f2bf(bp[i]);
        }
        __syncthreads();
        short8 bfr = *(const short8*)&Bl[(wave * 16 + lm) * 32 + quad * 8];
        #pragma unroll
        for (int mf = 0; mf < 4; ++mf) {
            short8 afr = *(const short8*)&Al[(mf * 16 + lm) * 32 + quad * 8];
            acc[mf] = __builtin_amdgcn_mfma_f32_16x16x32_bf16(afr, bfr, acc[mf], 0, 0, 0);
        }
        __syncthreads();
    }

    // epilogue: D layout n=lane&15, m=quad*4+reg
    const int n = n0 + wave * 16 + lm;
    const float bias = bx[n] + bh[n];
    #pragma unroll
    for (int mf = 0; mf < 4; ++mf)
        #pragma unroll
        for (int r = 0; r < 4; ++r) {
            int b = mf * 16 + quad * 4 + r;
            xw[((size_t)t0 * 64 + b) * HID + n] = f2bf(acc[mf][r] + bias);
        }
}

// ---------------------------------------------------------------------------
// k2: persistent scan. grid=64. cluster = blockIdx%8 (XCD-local by %8 swizzle),
// member = blockIdx/8. Cluster owns batch rows [8c, 8c+8) (padded to 16 in the
// MFMA M dim; pad rows read neighbor/slack data, results discarded). Member
// owns cols [64*member, 64*member+64); each of 4 waves owns 16 cols -> 16
// register-resident B-frags (64 VGPRs).
// ---------------------------------------------------------------------------
__global__ __launch_bounds__(256) void k2_scan(
    const ushort_t* __restrict__ xw, const float* __restrict__ Wh,
    ushort_t* __restrict__ h0, ushort_t* __restrict__ h1,
    uint_t* __restrict__ counters)
{
    const int cluster = blockIdx.x & 7;
    const int member  = blockIdx.x >> 3;
    const int rowbase = cluster * 8;
    const int tid  = threadIdx.x;
    const int wave = tid >> 6;
    const int lane = tid & 63;
    const int lm   = lane & 15;
    const int quad = lane >> 4;
    const int ncol = member * 64 + wave * 16 + lm;   // this lane's B/D column

    // Load W_h column-slice into B-fragment registers.
    // B[k][n]: lane holds n=lane&15(+base), k = kt*32 + quad*8 + j.
    short8 wf[16];
    #pragma unroll
    for (int kt = 0; kt < 16; ++kt) {
        short8 w;
        #pragma unroll
        for (int j = 0; j < 8; ++j)
            w[j] = (short)f2bf(Wh[(size_t)(kt * 32 + quad * 8 + j) * HID + ncol]);
        wf[kt] = w;
    }

    uint_t* cnt = counters + cluster * 16;   // 64B-spaced counters
    const int arow = rowbase + lm;           // A-frag row (rows >= rowbase+8 discarded)

    for (int t = 0; t < T_STEPS; ++t) {
        const ushort_t* hsrc = (t & 1) ? h1 : h0;
        ushort_t*       hdst = (t & 1) ? h0 : h1;

        // acc init = xw chunk (only real rows m<8 -> quad<2)
        f32x4 a0 = (f32x4){0.f, 0.f, 0.f, 0.f};
        f32x4 a1 = (f32x4){0.f, 0.f, 0.f, 0.f};
        #pragma unroll
        for (int r = 0; r < 4; ++r) {
            float v = 0.f;
            if (quad < 2)
                v = bf2f(xw[((size_t)t * 64 + rowbase + quad * 4 + r) * HID + ncol]);
            a0[r] = v;
        }

        // A-frags straight from global h (A[m=lane&15][k=quad*8+j], contig 16B)
        const ushort_t* ap = hsrc + (size_t)arow * HID + quad * 8;
        #pragma unroll
        for (int kt = 0; kt < 16; kt += 2) {   // 2 accum chains for MFMA latency
            short8 af0 = *(const short8*)(ap + kt * 32);
            short8 af1 = *(const short8*)(ap + kt * 32 + 32);
            a0 = __builtin_amdgcn_mfma_f32_16x16x32_bf16(af0, wf[kt],     a0, 0, 0, 0);
            a1 = __builtin_amdgcn_mfma_f32_16x16x32_bf16(af1, wf[kt + 1], a1, 0, 0, 0);
        }

        if (quad < 2) {
            #pragma unroll
            for (int r = 0; r < 4; ++r) {
                float s = a0[r] + a1[r];
                hdst[(size_t)(rowbase + quad * 4 + r) * HID + ncol] = f2bf(tanhf(s));
            }
        }

        if (t < T_STEPS - 1) {
            __syncthreads();                       // drains vmcnt -> stores in L2
            if (tid == 0) {
                __threadfence();                   // release (L2 writeback, device scope)
                atomicAdd(cnt, 1u);
                const uint_t target = 8u * (uint_t)(t + 1);
                while (__hip_atomic_load(cnt, __ATOMIC_RELAXED, __HIP_MEMORY_SCOPE_AGENT) < target)
                    __builtin_amdgcn_s_sleep(1);
            }
            __syncthreads();
            __threadfence();                       // acquire (invalidate before h reads)
        }
    }
}

// ---------------------------------------------------------------------------
// k3: out[b] = h_T[b,:] @ W_fc + b_fc.  64 blocks x 1 wave.
// ---------------------------------------------------------------------------
__global__ __launch_bounds__(64) void k3_out(
    const ushort_t* __restrict__ hfin, const float* __restrict__ Wfc,
    const float* __restrict__ bfc, float* __restrict__ out)
{
    const int b = blockIdx.x, lane = threadIdx.x;
    float s = 0.f;
    #pragma unroll
    for (int i = 0; i < 8; ++i) {
        int j = i * 64 + lane;
        s += bf2f(hfin[b * HID + j]) * Wfc[j];
    }
    #pragma unroll
    for (int off = 32; off; off >>= 1) s += __shfl_down(s, off, 64);
    if (lane == 0) out[b] = s + bfc[0];
}

// ---------------------------------------------------------------------------
extern "C" void kernel_launch(void* const* d_in, const int* in_sizes, int n_in,
                              void* d_out, int out_size, void* d_ws, size_t ws_size,
                              hipStream_t stream)
{
    const float* x   = (const float*)d_in[0];
    const float* Wx  = (const float*)d_in[1];
    const float* bx  = (const float*)d_in[2];
    const float* Wh  = (const float*)d_in[3];
    const float* bh  = (const float*)d_in[4];
    const float* Wfc = (const float*)d_in[5];
    const float* bfc = (const float*)d_in[6];
    float* out = (float*)d_out;

    char* ws = (char*)d_ws;
    // ws layout:
    //   [0, 67108864)            xw bf16 [1024][64][512]
    //   [67108864, +81920)       h0 bf16 [80][512] (rows 64..79 = zero slack)
    //   [67190784, +81920)       h1
    //   [67272704, +512)         cluster counters (8 x 64B-spaced u32)
    ushort_t* xw = (ushort_t*)ws;
    ushort_t* h0 = (ushort_t*)(ws + 67108864);
    ushort_t* h1 = (ushort_t*)(ws + 67108864 + 81920);
    uint_t* counters = (uint_t*)(ws + 67108864 + 163840);

    // zero h buffers (h_0 = 0, slack rows stay 0) + counters, every launch
    hipMemsetAsync(ws + 67108864, 0, 163840 + 512, stream);

    k1_xproj<<<dim3(8, 1024), 256, 0, stream>>>(x, Wx, bx, bh, xw);
    k2_scan <<<dim3(64),      256, 0, stream>>>(xw, Wh, h0, h1, counters);
    k3_out  <<<dim3(64),       64, 0, stream>>>(h0, Wfc, bfc, out);
}